// Round 2
// baseline (860.824 us; speedup 1.0000x reference)
//
#include <hip/hip_runtime.h>

typedef unsigned short u16;
typedef unsigned int u32;
typedef __attribute__((ext_vector_type(8))) short short8;
typedef __attribute__((ext_vector_type(4))) float f32x4;

__device__ __forceinline__ float b2f(u32 u) {
    union { u32 i; float f; } x; x.i = u << 16; return x.f;
}
__device__ __forceinline__ u16 f2b(float f) {
    union { float f; u32 i; } x; x.f = f;
    u32 u = x.i;
    u += 0x7fffu + ((u >> 16) & 1u);
    return (u16)(u >> 16);
}
__device__ __forceinline__ u32 pack2(float a, float b) {
    return (u32)f2b(a) | ((u32)f2b(b) << 16);
}
__device__ __forceinline__ void gl_lds16(const u16* g, u16* l) {
    __builtin_amdgcn_global_load_lds(
        (const __attribute__((address_space(1))) u32*)g,
        (__attribute__((address_space(3))) u32*)l, 16, 0, 0);
}
// inline-asm LDS read: invisible to SIInsertWaitcnts' LDS-DMA hazard tracking,
// so the counted-vmcnt pipeline isn't drained before every fragment read.
// Ordering vs MFMA is handled manually: lgkmcnt(0) + sched_barrier(0) (rule 18).
__device__ __forceinline__ short8 ds_read128(u32 off) {
    short8 r;
    asm volatile("ds_read_b128 %0, %1" : "=v"(r) : "v"(off));
    return r;
}

// ---------------- rope tables: cos/sin for 16384 positions x 32 pairs ----------------
__global__ void rope_tab(float* __restrict__ cosT, float* __restrict__ sinT) {
    int idx = blockIdx.x * 256 + threadIdx.x;      // < 524288
    int n = idx >> 5, i = idx & 31;
    float inv = exp2f(-(float)i * 0.41524101186091903f);  // log2(10000)/32
    float ang = (float)n * inv;
    float s, c;
    sincosf(ang, &s, &c);
    cosT[idx] = c; sinT[idx] = s;
}

// ---------------- weight convert + transpose to bf16 N-major ----------------
__global__ void conv_w(const float* __restrict__ Wq, const float* __restrict__ Wkv,
                       const float* __restrict__ Wo,
                       u16* __restrict__ wqkvT, u16* __restrict__ woT) {
    int idx = blockIdx.x * 256 + threadIdx.x;      // < 1048576
    if (idx < 786432) {                            // 1536 x 512
        int n = idx >> 9, k = idx & 511;
        float v = (n < 512) ? Wq[k * 512 + n] : Wkv[k * 1024 + (n - 512)];
        wqkvT[idx] = f2b(v);
    } else {
        int j = idx - 786432;                      // 512 x 512
        int n = j >> 9, k = j & 511;
        woT[j] = f2b(Wo[k * 512 + n]);
    }
}

// ---------------- RMSNorm: one wave per 512-col row, bf16 out ----------------
__launch_bounds__(256)
__global__ void rmsnorm_k(const float* __restrict__ x, const float* __restrict__ g,
                          u16* __restrict__ xn) {
    int row  = blockIdx.x * 4 + (threadIdx.x >> 6);
    int lane = threadIdx.x & 63;
    const float4* p = (const float4*)(x + (size_t)row * 512);
    float4 a = p[lane * 2], b = p[lane * 2 + 1];
    float ss = a.x*a.x + a.y*a.y + a.z*a.z + a.w*a.w
             + b.x*b.x + b.y*b.y + b.z*b.z + b.w*b.w;
#pragma unroll
    for (int off = 1; off < 64; off <<= 1) ss += __shfl_xor(ss, off);
    float scale = rsqrtf(ss * (1.0f / 512.0f) + 1.1920929e-07f);
    const float4* gp = (const float4*)g;
    float4 g0 = gp[lane * 2], g1 = gp[lane * 2 + 1];
    uint4 u;
    u.x = pack2(a.x * scale * g0.x, a.y * scale * g0.y);
    u.y = pack2(a.z * scale * g0.z, a.w * scale * g0.w);
    u.z = pack2(b.x * scale * g1.x, b.y * scale * g1.y);
    u.w = pack2(b.z * scale * g1.z, b.w * scale * g1.w);
    *(uint4*)(xn + (size_t)row * 512 + lane * 8) = u;
}

// ---------------- GEMM, 256x256 tile, BK=64, 8-wave, 8-phase counted-vmcnt ----------------
// Schedule (per main iter, 2 K-tiles: 2i -> buf0, 2i+1 -> buf1):
//  ph1: read A0,B0[buf0]; stage Ah1(2i+1)->buf1 | ph2: read B1; stage Ah0(2i+2)
//  ph3: read A1; stage Bh0(2i+2)               | ph4: stage Bh1(2i+2); vmcnt(6)
//  ph5: read A0,B0[buf1]; stage Ah1(2i+2)      | ph6: read B1; stage Ah0(2i+3)
//  ph7: read A1; stage Bh0(2i+3)               | ph8: stage Bh1(2i+3); vmcnt(6)
// Ledger (loads; 2 per STAGE): ph4's vmcnt(6) leaves {ph2,3,4}; ph8's vmcnt(6)
// leaves {ph6,7,8} — every consuming read is covered (verified r1 post-mortem).
// Fragment reads are inline-asm ds_read_b128 so the compiler's LDS-DMA hazard
// tracking cannot inject vmcnt(0) drains per phase (round-1 failure mode).
// MODE 0: M=65536,N=1536 (q|k|v), 1536 blocks; reversed-batch A rows for n0>=512.
// MODE 1: M=65536,N=512, 512 blocks, fp32 epilogue.
template <int MODE>
__launch_bounds__(512, 2)
__global__ void gemm8p(const u16* __restrict__ A, const u16* __restrict__ Bt,
                       u16* __restrict__ oq, u16* __restrict__ ok,
                       u16* __restrict__ ov, float* __restrict__ of) {
    __shared__ u16 As[2][16384];   // 2 x 256 rows x 64 cols bf16 (32 KB each)
    __shared__ u16 Bs[2][16384];
    const int tid  = threadIdx.x;
    const int lane = tid & 63, w = tid >> 6;       // 8 waves
    const int wm = w >> 2, wn = w & 3;             // 2 x 4 wave grid
    const int l15 = lane & 15, l4 = lane >> 4;
    const int lr = lane >> 3;
    const int sg8 = (((lane & 7) ^ lr)) * 8;       // XOR-swizzled source chunk (u16 elems)
    const int bc0 = (w >> 1) * 8 + (w & 1) * 2;    // B staging chunk base

    // LDS byte-offset bases (low 32 bits of flat shared address = LDS offset)
    const u32 asb0 = (u32)(uintptr_t)&As[0][0];
    const u32 asb1 = (u32)(uintptr_t)&As[1][0];
    const u32 bsb0 = (u32)(uintptr_t)&Bs[0][0];
    const u32 bsb1 = (u32)(uintptr_t)&Bs[1][0];

    const int idx = blockIdx.x;
    const int xcd = idx & 7, rest = idx >> 3;
    int j, mg;
    if (MODE == 0) { j = rest % 6; mg = rest / 6; }
    else           { j = rest & 1; mg = rest >> 1; }
    const int t0 = (mg * 8 + xcd) * 256;
    const int n0 = j * 256;
    int arow0 = t0;
    if (MODE == 0 && n0 >= 512) {
        int b = t0 >> 14;
        arow0 = (((b + 2) & 3) << 14) | (t0 & 16383);
    }

#define STAGE_A(buf, h, kt) do {                                                             \
        int c0_ = (h) * 8 + w;                                                               \
        gl_lds16(A + (size_t)(arow0 + c0_ * 8 + lr) * 512 + (kt) * 64 + sg8,                 \
                 &As[buf][c0_ * 512]);                                                       \
        int c1_ = c0_ + 16;                                                                  \
        gl_lds16(A + (size_t)(arow0 + c1_ * 8 + lr) * 512 + (kt) * 64 + sg8,                 \
                 &As[buf][c1_ * 512]);                                                       \
    } while (0)
#define STAGE_B(buf, h, kt) do {                                                             \
        int c0_ = bc0 + (h) * 4;                                                             \
        gl_lds16(Bt + (size_t)(n0 + c0_ * 8 + lr) * 512 + (kt) * 64 + sg8,                   \
                 &Bs[buf][c0_ * 512]);                                                       \
        int c1_ = c0_ + 1;                                                                   \
        gl_lds16(Bt + (size_t)(n0 + c1_ * 8 + lr) * 512 + (kt) * 64 + sg8,                   \
                 &Bs[buf][c1_ * 512]);                                                       \
    } while (0)
#define LDA(rb, mh) do {                                                                     \
        const u32 ab_ = (rb) ? asb1 : asb0;                                                  \
        _Pragma("unroll") for (int mi_ = 0; mi_ < 4; ++mi_) {                                \
            int row_ = wm * 128 + ((mh) * 4 + mi_) * 16 + l15;                               \
            _Pragma("unroll") for (int ks_ = 0; ks_ < 2; ++ks_) {                            \
                int ch_ = (ks_ * 4 + l4) ^ (row_ & 7);                                       \
                aF[mi_][ks_] = ds_read128(ab_ + (u32)(row_ * 128 + ch_ * 16));               \
            } } } while (0)
#define LDB(rb, nh) do {                                                                     \
        const u32 bb_ = (rb) ? bsb1 : bsb0;                                                  \
        _Pragma("unroll") for (int ni_ = 0; ni_ < 2; ++ni_) {                                \
            int row_ = wn * 64 + ((nh) * 2 + ni_) * 16 + l15;                                \
            _Pragma("unroll") for (int ks_ = 0; ks_ < 2; ++ks_) {                            \
                int ch_ = (ks_ * 4 + l4) ^ (row_ & 7);                                       \
                bF[(nh) * 2 + ni_][ks_] = ds_read128(bb_ + (u32)(row_ * 128 + ch_ * 16));    \
            } } } while (0)
#define MMA(mh, nh) do {                                                                     \
        _Pragma("unroll") for (int mi_ = 0; mi_ < 4; ++mi_)                                  \
        _Pragma("unroll") for (int ni_ = 0; ni_ < 2; ++ni_)                                  \
        _Pragma("unroll") for (int ks_ = 0; ks_ < 2; ++ks_)                                  \
            acc[(mh) * 4 + mi_][(nh) * 2 + ni_] = __builtin_amdgcn_mfma_f32_16x16x32_bf16(   \
                aF[mi_][ks_], bF[(nh) * 2 + ni_][ks_],                                       \
                acc[(mh) * 4 + mi_][(nh) * 2 + ni_], 0, 0, 0);                               \
    } while (0)
#define BARR() __builtin_amdgcn_s_barrier()
#define LGKM0() do { asm volatile("s_waitcnt lgkmcnt(0)" ::: "memory");                      \
                     __builtin_amdgcn_sched_barrier(0); } while (0)

    f32x4 acc[8][4];
#pragma unroll
    for (int mi = 0; mi < 8; ++mi)
#pragma unroll
        for (int ni = 0; ni < 4; ++ni) acc[mi][ni] = (f32x4){0.f, 0.f, 0.f, 0.f};
    short8 aF[4][2], bF[4][2];

    // prologue: tile0 complete + tile1 {Ah0,Bh0,Bh1}; drain, barrier
    STAGE_A(0, 0, 0); STAGE_A(0, 1, 0); STAGE_B(0, 0, 0); STAGE_B(0, 1, 0);
    STAGE_A(1, 0, 1); STAGE_B(1, 0, 1); STAGE_B(1, 1, 1);
    asm volatile("s_waitcnt vmcnt(0)" ::: "memory");
    __builtin_amdgcn_s_barrier();
    __builtin_amdgcn_sched_barrier(0);

    for (int i = 0; i < 4; ++i) {
        const int kt2 = 2 * i + 2, kt3 = 2 * i + 3;
        const bool st = (i < 3);
        // ph1
        LDA(0, 0); LDB(0, 0);
        STAGE_A(1, 1, 2 * i + 1);
        BARR(); LGKM0();
        __builtin_amdgcn_s_setprio(1); MMA(0, 0); __builtin_amdgcn_s_setprio(0);
        BARR();
        // ph2
        LDB(0, 1);
        if (st) STAGE_A(0, 0, kt2);
        BARR(); LGKM0();
        __builtin_amdgcn_s_setprio(1); MMA(0, 1); __builtin_amdgcn_s_setprio(0);
        BARR();
        // ph3
        LDA(0, 1);
        if (st) STAGE_B(0, 0, kt2);
        BARR(); LGKM0();
        __builtin_amdgcn_s_setprio(1); MMA(1, 0); __builtin_amdgcn_s_setprio(0);
        BARR();
        // ph4  (vmcnt before the barrier so all waves' prefetches are landed for ph5+)
        if (st) STAGE_B(0, 1, kt2);
        BARR(); LGKM0();
        __builtin_amdgcn_s_setprio(1); MMA(1, 1); __builtin_amdgcn_s_setprio(0);
        if (st) { asm volatile("s_waitcnt vmcnt(6)" ::: "memory"); }
        else    { asm volatile("s_waitcnt vmcnt(0)" ::: "memory"); }
        BARR();
        // ph5
        LDA(1, 0); LDB(1, 0);
        if (st) STAGE_A(0, 1, kt2);
        BARR(); LGKM0();
        __builtin_amdgcn_s_setprio(1); MMA(0, 0); __builtin_amdgcn_s_setprio(0);
        BARR();
        // ph6
        LDB(1, 1);
        if (st) STAGE_A(1, 0, kt3);
        BARR(); LGKM0();
        __builtin_amdgcn_s_setprio(1); MMA(0, 1); __builtin_amdgcn_s_setprio(0);
        BARR();
        // ph7
        LDA(1, 1);
        if (st) STAGE_B(1, 0, kt3);
        BARR(); LGKM0();
        __builtin_amdgcn_s_setprio(1); MMA(1, 0); __builtin_amdgcn_s_setprio(0);
        BARR();
        // ph8
        if (st) STAGE_B(1, 1, kt3);
        BARR(); LGKM0();
        __builtin_amdgcn_s_setprio(1); MMA(1, 1); __builtin_amdgcn_s_setprio(0);
        asm volatile("s_waitcnt vmcnt(6)" ::: "memory");
        BARR();
    }

    // epilogue: C row = (l4*4+r), col = l15 within each 16x16 tile
#pragma unroll
    for (int mi = 0; mi < 8; ++mi) {
#pragma unroll
        for (int ni = 0; ni < 4; ++ni) {
#pragma unroll
            for (int r = 0; r < 4; ++r) {
                int grow = t0 + wm * 128 + mi * 16 + l4 * 4 + r;
                int gcol = n0 + wn * 64 + ni * 16 + l15;
                float val = acc[mi][ni][r];
                if (MODE == 1) {
                    of[(size_t)grow * 512 + gcol] = val;
                } else {
                    if (n0 < 512) {
                        oq[(size_t)grow * 512 + gcol] = f2b(val);
                    } else if (n0 < 1024) {
                        ok[(size_t)grow * 512 + (gcol - 512)] = f2b(val);
                    } else {
                        int c = gcol - 1024;
                        ov[(size_t)grow * 512 + c] = f2b(val);
                        int bb = grow >> 14, nn = grow & 16383;
                        of[((size_t)(bb * 8 + (c >> 6)) << 20) + (size_t)nn * 64 + (c & 63)] = val;
                    }
                }
            }
        }
    }
#undef STAGE_A
#undef STAGE_B
#undef LDA
#undef LDB
#undef MMA
#undef BARR
#undef LGKM0
}

// ---------------- windowed attention: one block per (b, window, head) ----------------
// Q 64x64, K/V 68x64 (4 persistent-mem + 64 tokens), RoPE fused at staging.
__launch_bounds__(256)
__global__ void attn_win(const u16* __restrict__ q_buf, const u16* __restrict__ k_buf,
                         const u16* __restrict__ v_buf, const float* __restrict__ tm,
                         const float* __restrict__ cosT, const float* __restrict__ sinT,
                         u16* __restrict__ o_buf) {
    __shared__ u16 qs[64 * 72];    // [qrow][dh],  stride 72 bf16 (144 B)
    __shared__ u16 ks[80 * 72];    // [key][dh],   rows 0-3 pm, 4-67 tokens, 68-79 zero
    __shared__ u16 vt[64 * 104];   // [dh][key],   stride 104 bf16; keys 68-95 zeroed
    __shared__ u16 ps[64 * 104];   // [qrow][key]; cols 0-95 written in softmax (80-95 = 0)
    const int tid  = threadIdx.x;
    const int lane = tid & 63, w = tid >> 6;
    const int l15 = lane & 15, l4 = lane >> 4;
    const int h = blockIdx.x, wi = blockIdx.y, b = blockIdx.z;
    const int t0 = b * 16384 + wi * 64;

    // zero only what's read-but-unwritten: vt keys 68..95 (14 u32/row), ks rows 68..79
    for (int i = tid; i < 896; i += 256) {
        int d = i / 14, c = i - d * 14;
        *(u32*)&vt[d * 104 + 68 + 2 * c] = 0u;
    }
    for (int i = tid; i < 432; i += 256) ((u32*)ks)[2448 + i] = 0u;   // ks rows 68..79

    // stage task-memory (disjoint from zero regions; no barrier needed yet)
    {
        int r = tid >> 6, d = tid & 63;    // 256 threads == 4x64
        ks[r * 72 + d]   = f2b(tm[(h * 4 + r) * 64 + d]);
        vt[d * 104 + r]  = f2b(tm[2048 + (h * 4 + r) * 64 + d]);
    }
    // stage Q/K with rope
#pragma unroll
    for (int p = tid; p < 2048; p += 256) {
        int row = p >> 5, i = p & 31;
        int n = wi * 64 + row;
        float c = cosT[n * 32 + i], s = sinT[n * 32 + i];
        size_t gbase = (size_t)(t0 + row) * 512 + h * 64 + 2 * i;
        u32 qv = *(const u32*)(q_buf + gbase);
        float x0 = b2f(qv & 0xffffu), x1 = b2f(qv >> 16);
        *(u32*)&qs[row * 72 + 2 * i] = pack2(x0 * c - x1 * s, x1 * c + x0 * s);
        u32 kv = *(const u32*)(k_buf + gbase);
        x0 = b2f(kv & 0xffffu); x1 = b2f(kv >> 16);
        *(u32*)&ks[(row + 4) * 72 + 2 * i] = pack2(x0 * c - x1 * s, x1 * c + x0 * s);
    }
    // stage V transposed (u32 global loads, two u16 LDS stores)
#pragma unroll
    for (int p = tid; p < 2048; p += 256) {
        int row = p >> 5, e = p & 31;
        u32 vv = *(const u32*)(v_buf + (size_t)(t0 + row) * 512 + h * 64 + 2 * e);
        vt[(2 * e) * 104 + 4 + row]     = (u16)(vv & 0xffffu);
        vt[(2 * e + 1) * 104 + 4 + row] = (u16)(vv >> 16);
    }
    __syncthreads();

    // S = Q K^T (wave w owns q-rows [w*16, w*16+16))
    f32x4 sacc[5];
#pragma unroll
    for (int nt = 0; nt < 5; ++nt) sacc[nt] = (f32x4){0.f, 0.f, 0.f, 0.f};
#pragma unroll
    for (int ksi = 0; ksi < 2; ++ksi) {
        short8 a = *(const short8*)&qs[(w * 16 + l15) * 72 + ksi * 32 + l4 * 8];
#pragma unroll
        for (int nt = 0; nt < 5; ++nt) {
            short8 bfr = *(const short8*)&ks[(nt * 16 + l15) * 72 + ksi * 32 + l4 * 8];
            sacc[nt] = __builtin_amdgcn_mfma_f32_16x16x32_bf16(a, bfr, sacc[nt], 0, 0, 0);
        }
    }
    // softmax (rows = w*16 + l4*4 + r; cols spread over 16 lanes x 5 tiles)
    float inv_l[4];
#pragma unroll
    for (int r = 0; r < 4; ++r) {
        float sv[5];
#pragma unroll
        for (int nt = 0; nt < 5; ++nt) {
            float x = sacc[nt][r] * 0.125f;
            if (nt == 4 && l15 >= 4) x = -1e30f;   // keys >= 68 masked
            sv[nt] = x;
        }
        float m = sv[0];
#pragma unroll
        for (int nt = 1; nt < 5; ++nt) m = fmaxf(m, sv[nt]);
#pragma unroll
        for (int off = 1; off < 16; off <<= 1) m = fmaxf(m, __shfl_xor(m, off));
        float sum = 0.f;
#pragma unroll
        for (int nt = 0; nt < 5; ++nt) { sv[nt] = __expf(sv[nt] - m); sum += sv[nt]; }
#pragma unroll
        for (int off = 1; off < 16; off <<= 1) sum += __shfl_xor(sum, off);
        inv_l[r] = 1.f / sum;
        int prow = w * 16 + l4 * 4 + r;
#pragma unroll
        for (int nt = 0; nt < 5; ++nt) ps[prow * 104 + nt * 16 + l15] = f2b(sv[nt]);
        ps[prow * 104 + 80 + l15] = 0;   // pad keys 80..95 for the ksi=2 PV step
    }
    __syncthreads();

    // O = P V  (K-dim padded to 96)
    f32x4 oacc[4];
#pragma unroll
    for (int dt = 0; dt < 4; ++dt) oacc[dt] = (f32x4){0.f, 0.f, 0.f, 0.f};
#pragma unroll
    for (int ksi = 0; ksi < 3; ++ksi) {
        short8 a = *(const short8*)&ps[(w * 16 + l15) * 104 + ksi * 32 + l4 * 8];
#pragma unroll
        for (int dt = 0; dt < 4; ++dt) {
            short8 bfr = *(const short8*)&vt[(dt * 16 + l15) * 104 + ksi * 32 + l4 * 8];
            oacc[dt] = __builtin_amdgcn_mfma_f32_16x16x32_bf16(a, bfr, oacc[dt], 0, 0, 0);
        }
    }
#pragma unroll
    for (int dt = 0; dt < 4; ++dt)
#pragma unroll
        for (int r = 0; r < 4; ++r) {
            int row = w * 16 + l4 * 4 + r;
            o_buf[(size_t)(t0 + row) * 512 + h * 64 + dt * 16 + l15] =
                f2b(oacc[dt][r] * inv_l[r]);
        }
}

// ---------------- launch ----------------
extern "C" void kernel_launch(void* const* d_in, const int* in_sizes, int n_in,
                              void* d_out, int out_size, void* d_ws, size_t ws_size,
                              hipStream_t stream) {
    const float* seq    = (const float*)d_in[0];
    const float* norm_w = (const float*)d_in[5];
    const float* Wq     = (const float*)d_in[6];
    const float* Wkv    = (const float*)d_in[7];
    const float* Wo     = (const float*)d_in[8];
    const float* tmem   = (const float*)d_in[9];
    float* out   = (float*)d_out;
    float* origv = out + 33554432;          // (B=4, h=8, N=16384, d=64)

    char* ws = (char*)d_ws;
    u16* xn    = (u16*)(ws);                 // 64 MB; reused as attn_out after qkv GEMM
    u16* q_buf = (u16*)(ws + 67108864);
    u16* k_buf = (u16*)(ws + 134217728);
    u16* v_buf = (u16*)(ws + 201326592);
    u16* wqkvT = (u16*)(ws + 268435456);     // 1536x512 bf16
    u16* woT   = (u16*)(ws + 268435456 + 1572864);   // 512x512 bf16
    float* cosT = (float*)(ws + 270532608);  // 16384x32
    float* sinT = cosT + 524288;

    rope_tab<<<2048, 256, 0, stream>>>(cosT, sinT);
    conv_w<<<4096, 256, 0, stream>>>(Wq, Wkv, Wo, wqkvT, woT);
    rmsnorm_k<<<16384, 256, 0, stream>>>(seq, norm_w, xn);
    gemm8p<0><<<1536, 512, 0, stream>>>(xn, wqkvT, q_buf, k_buf, v_buf, origv);
    attn_win<<<dim3(8, 256, 4), 256, 0, stream>>>(q_buf, k_buf, v_buf, tmem, cosT, sinT, xn);
    gemm8p<1><<<512, 512, 0, stream>>>(xn, woT, nullptr, nullptr, nullptr, out);
}

// Round 3
// 650.066 us; speedup vs baseline: 1.3242x; 1.3242x over previous
//
#include <hip/hip_runtime.h>

typedef unsigned short u16;
typedef unsigned int u32;
typedef __attribute__((ext_vector_type(8))) short short8;
typedef __attribute__((ext_vector_type(4))) float f32x4;

__device__ __forceinline__ float b2f(u32 u) {
    union { u32 i; float f; } x; x.i = u << 16; return x.f;
}
__device__ __forceinline__ u16 f2b(float f) {
    union { float f; u32 i; } x; x.f = f;
    u32 u = x.i;
    u += 0x7fffu + ((u >> 16) & 1u);
    return (u16)(u >> 16);
}
__device__ __forceinline__ u32 pack2(float a, float b) {
    return (u32)f2b(a) | ((u32)f2b(b) << 16);
}
__device__ __forceinline__ void gl_lds16(const u16* g, u16* l) {
    __builtin_amdgcn_global_load_lds(
        (const __attribute__((address_space(1))) u32*)g,
        (__attribute__((address_space(3))) u32*)l, 16, 0, 0);
}
// inline-asm LDS read with compile-time offset immediate: invisible to the
// compiler's LDS-DMA hazard tracking (no per-phase vmcnt(0) drains) AND no
// per-read address VALU/VGPR cost (round-2 spill fix). Ordering vs MFMA is
// manual: lgkmcnt(0) + sched_barrier(0) (rule 18).
#define DSR_C(O) else if constexpr (OFF == O) \
    asm volatile("ds_read_b128 %0, %1 offset:" #O : "=v"(r) : "v"(b))
template <int OFF>
__device__ __forceinline__ short8 dsr(u32 b) {
    short8 r;
    if constexpr (OFF == 0) asm volatile("ds_read_b128 %0, %1" : "=v"(r) : "v"(b));
    DSR_C(2048); DSR_C(4096); DSR_C(6144); DSR_C(8192); DSR_C(10240);
    DSR_C(12288); DSR_C(14336); DSR_C(32768); DSR_C(34816); DSR_C(36864);
    DSR_C(38912); DSR_C(40960); DSR_C(43008); DSR_C(45056); DSR_C(47104);
    else asm volatile("ds_read_b128 %0, %1" : "=v"(r) : "v"(b + OFF));
    return r;
}

// ---------------- rope tables: cos/sin for 16384 positions x 32 pairs ----------------
__global__ void rope_tab(float* __restrict__ cosT, float* __restrict__ sinT) {
    int idx = blockIdx.x * 256 + threadIdx.x;      // < 524288
    int n = idx >> 5, i = idx & 31;
    float inv = exp2f(-(float)i * 0.41524101186091903f);  // log2(10000)/32
    float ang = (float)n * inv;
    float s, c;
    sincosf(ang, &s, &c);
    cosT[idx] = c; sinT[idx] = s;
}

// ---------------- weight convert + transpose to bf16 N-major ----------------
__global__ void conv_w(const float* __restrict__ Wq, const float* __restrict__ Wkv,
                       const float* __restrict__ Wo,
                       u16* __restrict__ wqkvT, u16* __restrict__ woT) {
    int idx = blockIdx.x * 256 + threadIdx.x;      // < 1048576
    if (idx < 786432) {                            // 1536 x 512
        int n = idx >> 9, k = idx & 511;
        float v = (n < 512) ? Wq[k * 512 + n] : Wkv[k * 1024 + (n - 512)];
        wqkvT[idx] = f2b(v);
    } else {
        int j = idx - 786432;                      // 512 x 512
        int n = j >> 9, k = j & 511;
        woT[j] = f2b(Wo[k * 512 + n]);
    }
}

// ---------------- RMSNorm: one wave per 512-col row, bf16 out ----------------
__launch_bounds__(256)
__global__ void rmsnorm_k(const float* __restrict__ x, const float* __restrict__ g,
                          u16* __restrict__ xn) {
    int row  = blockIdx.x * 4 + (threadIdx.x >> 6);
    int lane = threadIdx.x & 63;
    const float4* p = (const float4*)(x + (size_t)row * 512);
    float4 a = p[lane * 2], b = p[lane * 2 + 1];
    float ss = a.x*a.x + a.y*a.y + a.z*a.z + a.w*a.w
             + b.x*b.x + b.y*b.y + b.z*b.z + b.w*b.w;
#pragma unroll
    for (int off = 1; off < 64; off <<= 1) ss += __shfl_xor(ss, off);
    float scale = rsqrtf(ss * (1.0f / 512.0f) + 1.1920929e-07f);
    const float4* gp = (const float4*)g;
    float4 g0 = gp[lane * 2], g1 = gp[lane * 2 + 1];
    uint4 u;
    u.x = pack2(a.x * scale * g0.x, a.y * scale * g0.y);
    u.y = pack2(a.z * scale * g0.z, a.w * scale * g0.w);
    u.z = pack2(b.x * scale * g1.x, b.y * scale * g1.y);
    u.w = pack2(b.z * scale * g1.z, b.w * scale * g1.w);
    *(uint4*)(xn + (size_t)row * 512 + lane * 8) = u;
}

// ---------------- GEMM, 256x256 tile, BK=64, 8-wave, 8-phase counted-vmcnt ----------------
// Schedule (per main iter, 2 K-tiles: 2i -> buf0, 2i+1 -> buf1):
//  ph1: read A0,B0[buf0]; stage Ah1(2i+1)->buf1 | ph2: read B1; stage Ah0(2i+2)
//  ph3: read A1; stage Bh0(2i+2)               | ph4: stage Bh1(2i+2); vmcnt(6)
//  ph5: read A0,B0[buf1]; stage Ah1(2i+2)      | ph6: read B1; stage Ah0(2i+3)
//  ph7: read A1; stage Bh0(2i+3)               | ph8: stage Bh1(2i+3); vmcnt(6)
// Ledger verified (r1/r2 post-mortems): ph4's vmcnt(6) leaves {ph2,3,4}; ph8's
// leaves {ph6,7,8}; every consuming read is covered; last iter drains vmcnt(0).
// Fragment reads: dsr<OFF> — 4 persistent base VGPRs + 16-bit DS offset imm.
// The swizzled chunk ch=(ks*4+l4)^(row&7) depends only on ks and l15&7, so
// base[ks] covers all (buf,mh,mi,nh,ni) via the immediate (r2 spill fix).
// MODE 0: M=65536,N=1536 (q|k|v), 1536 blocks; reversed-batch A rows for n0>=512.
// MODE 1: M=65536,N=512, 512 blocks, fp32 epilogue.
template <int MODE>
__launch_bounds__(512, 2)
__global__ void gemm8p(const u16* __restrict__ A, const u16* __restrict__ Bt,
                       u16* __restrict__ oq, u16* __restrict__ ok,
                       u16* __restrict__ ov, float* __restrict__ of) {
    __shared__ u16 As[2][16384];   // 2 x 256 rows x 64 cols bf16 (32 KB each)
    __shared__ u16 Bs[2][16384];
    const int tid  = threadIdx.x;
    const int lane = tid & 63, w = tid >> 6;       // 8 waves
    const int wm = w >> 2, wn = w & 3;             // 2 x 4 wave grid
    const int l15 = lane & 15, l4 = lane >> 4;
    const int lr = lane >> 3;
    const int sg8 = (((lane & 7) ^ lr)) * 8;       // XOR-swizzled source chunk (u16 elems)
    const int bc0 = (w >> 1) * 8 + (w & 1) * 2;    // B staging chunk base

    // ds_read base addresses (LDS byte offsets); buf1/fragment selects are imm offsets
    const u32 asb0 = (u32)(uintptr_t)&As[0][0];
    const u32 bsb0 = (u32)(uintptr_t)&Bs[0][0];
    const int chx0 = (l4) ^ (l15 & 7);            // ks=0 swizzled chunk
    const int chx1 = (4 + l4) ^ (l15 & 7);        // ks=1 swizzled chunk
    const u32 aB0 = asb0 + (u32)((wm * 128 + l15) * 128 + chx0 * 16);
    const u32 aB1 = asb0 + (u32)((wm * 128 + l15) * 128 + chx1 * 16);
    const u32 bB0 = bsb0 + (u32)((wn * 64 + l15) * 128 + chx0 * 16);
    const u32 bB1 = bsb0 + (u32)((wn * 64 + l15) * 128 + chx1 * 16);

    const int idx = blockIdx.x;
    const int xcd = idx & 7, rest = idx >> 3;
    int j, mg;
    if (MODE == 0) { j = rest % 6; mg = rest / 6; }
    else           { j = rest & 1; mg = rest >> 1; }
    const int t0 = (mg * 8 + xcd) * 256;
    const int n0 = j * 256;
    int arow0 = t0;
    if (MODE == 0 && n0 >= 512) {
        int b = t0 >> 14;
        arow0 = (((b + 2) & 3) << 14) | (t0 & 16383);
    }

#define STAGE_A(buf, h, kt) do {                                                             \
        int c0_ = (h) * 8 + w;                                                               \
        gl_lds16(A + (size_t)(arow0 + c0_ * 8 + lr) * 512 + (kt) * 64 + sg8,                 \
                 &As[buf][c0_ * 512]);                                                       \
        int c1_ = c0_ + 16;                                                                  \
        gl_lds16(A + (size_t)(arow0 + c1_ * 8 + lr) * 512 + (kt) * 64 + sg8,                 \
                 &As[buf][c1_ * 512]);                                                       \
    } while (0)
#define STAGE_B(buf, h, kt) do {                                                             \
        int c0_ = bc0 + (h) * 4;                                                             \
        gl_lds16(Bt + (size_t)(n0 + c0_ * 8 + lr) * 512 + (kt) * 64 + sg8,                   \
                 &Bs[buf][c0_ * 512]);                                                       \
        int c1_ = c0_ + 1;                                                                   \
        gl_lds16(Bt + (size_t)(n0 + c1_ * 8 + lr) * 512 + (kt) * 64 + sg8,                   \
                 &Bs[buf][c1_ * 512]);                                                       \
    } while (0)
#define LDA1(rb, mh, mi) do {                                                                \
        aF[mi][0] = dsr<(rb) * 32768 + (mh) * 8192 + (mi) * 2048>(aB0);                      \
        aF[mi][1] = dsr<(rb) * 32768 + (mh) * 8192 + (mi) * 2048>(aB1);                      \
    } while (0)
#define LDA(rb, mh) do { LDA1(rb, mh, 0); LDA1(rb, mh, 1); LDA1(rb, mh, 2); LDA1(rb, mh, 3); } while (0)
#define LDB1(rb, nh, ni) do {                                                                \
        bF[(nh) * 2 + (ni)][0] = dsr<(rb) * 32768 + ((nh) * 2 + (ni)) * 2048>(bB0);          \
        bF[(nh) * 2 + (ni)][1] = dsr<(rb) * 32768 + ((nh) * 2 + (ni)) * 2048>(bB1);          \
    } while (0)
#define LDB(rb, nh) do { LDB1(rb, nh, 0); LDB1(rb, nh, 1); } while (0)
#define MMA(mh, nh) do {                                                                     \
        _Pragma("unroll") for (int mi_ = 0; mi_ < 4; ++mi_)                                  \
        _Pragma("unroll") for (int ni_ = 0; ni_ < 2; ++ni_)                                  \
        _Pragma("unroll") for (int ks_ = 0; ks_ < 2; ++ks_)                                  \
            acc[(mh) * 4 + mi_][(nh) * 2 + ni_] = __builtin_amdgcn_mfma_f32_16x16x32_bf16(   \
                aF[mi_][ks_], bF[(nh) * 2 + ni_][ks_],                                       \
                acc[(mh) * 4 + mi_][(nh) * 2 + ni_], 0, 0, 0);                               \
    } while (0)
#define BARR() __builtin_amdgcn_s_barrier()
#define LGKM0() do { asm volatile("s_waitcnt lgkmcnt(0)" ::: "memory");                      \
                     __builtin_amdgcn_sched_barrier(0); } while (0)

    f32x4 acc[8][4];
#pragma unroll
    for (int mi = 0; mi < 8; ++mi)
#pragma unroll
        for (int ni = 0; ni < 4; ++ni) acc[mi][ni] = (f32x4){0.f, 0.f, 0.f, 0.f};
    short8 aF[4][2], bF[4][2];

    // prologue: tile0 complete + tile1 {Ah0,Bh0,Bh1}; drain, barrier
    STAGE_A(0, 0, 0); STAGE_A(0, 1, 0); STAGE_B(0, 0, 0); STAGE_B(0, 1, 0);
    STAGE_A(1, 0, 1); STAGE_B(1, 0, 1); STAGE_B(1, 1, 1);
    asm volatile("s_waitcnt vmcnt(0)" ::: "memory");
    __builtin_amdgcn_s_barrier();
    __builtin_amdgcn_sched_barrier(0);

    for (int i = 0; i < 4; ++i) {
        const int kt2 = 2 * i + 2, kt3 = 2 * i + 3;
        const bool st = (i < 3);
        // ph1
        LDA(0, 0); LDB(0, 0);
        STAGE_A(1, 1, 2 * i + 1);
        BARR(); LGKM0();
        __builtin_amdgcn_s_setprio(1); MMA(0, 0); __builtin_amdgcn_s_setprio(0);
        BARR();
        // ph2
        LDB(0, 1);
        if (st) STAGE_A(0, 0, kt2);
        BARR(); LGKM0();
        __builtin_amdgcn_s_setprio(1); MMA(0, 1); __builtin_amdgcn_s_setprio(0);
        BARR();
        // ph3
        LDA(0, 1);
        if (st) STAGE_B(0, 0, kt2);
        BARR(); LGKM0();
        __builtin_amdgcn_s_setprio(1); MMA(1, 0); __builtin_amdgcn_s_setprio(0);
        BARR();
        // ph4  (vmcnt before the barrier so all waves' prefetches are landed for ph5+)
        if (st) STAGE_B(0, 1, kt2);
        BARR(); LGKM0();
        __builtin_amdgcn_s_setprio(1); MMA(1, 1); __builtin_amdgcn_s_setprio(0);
        if (st) { asm volatile("s_waitcnt vmcnt(6)" ::: "memory"); }
        else    { asm volatile("s_waitcnt vmcnt(0)" ::: "memory"); }
        BARR();
        // ph5
        LDA(1, 0); LDB(1, 0);
        if (st) STAGE_A(0, 1, kt2);
        BARR(); LGKM0();
        __builtin_amdgcn_s_setprio(1); MMA(0, 0); __builtin_amdgcn_s_setprio(0);
        BARR();
        // ph6
        LDB(1, 1);
        if (st) STAGE_A(1, 0, kt3);
        BARR(); LGKM0();
        __builtin_amdgcn_s_setprio(1); MMA(0, 1); __builtin_amdgcn_s_setprio(0);
        BARR();
        // ph7
        LDA(1, 1);
        if (st) STAGE_B(1, 0, kt3);
        BARR(); LGKM0();
        __builtin_amdgcn_s_setprio(1); MMA(1, 0); __builtin_amdgcn_s_setprio(0);
        BARR();
        // ph8
        if (st) STAGE_B(1, 1, kt3);
        BARR(); LGKM0();
        __builtin_amdgcn_s_setprio(1); MMA(1, 1); __builtin_amdgcn_s_setprio(0);
        asm volatile("s_waitcnt vmcnt(6)" ::: "memory");
        BARR();
    }

    // epilogue: C row = (l4*4+r), col = l15 within each 16x16 tile
#pragma unroll
    for (int mi = 0; mi < 8; ++mi) {
#pragma unroll
        for (int ni = 0; ni < 4; ++ni) {
#pragma unroll
            for (int r = 0; r < 4; ++r) {
                int grow = t0 + wm * 128 + mi * 16 + l4 * 4 + r;
                int gcol = n0 + wn * 64 + ni * 16 + l15;
                float val = acc[mi][ni][r];
                if (MODE == 1) {
                    of[(size_t)grow * 512 + gcol] = val;
                } else {
                    if (n0 < 512) {
                        oq[(size_t)grow * 512 + gcol] = f2b(val);
                    } else if (n0 < 1024) {
                        ok[(size_t)grow * 512 + (gcol - 512)] = f2b(val);
                    } else {
                        int c = gcol - 1024;
                        ov[(size_t)grow * 512 + c] = f2b(val);
                        int bb = grow >> 14, nn = grow & 16383;
                        of[((size_t)(bb * 8 + (c >> 6)) << 20) + (size_t)nn * 64 + (c & 63)] = val;
                    }
                }
            }
        }
    }
#undef STAGE_A
#undef STAGE_B
#undef LDA1
#undef LDA
#undef LDB1
#undef LDB
#undef MMA
#undef BARR
#undef LGKM0
}

// ---------------- windowed attention: one block per (b, window, head) ----------------
// Q 64x64, K/V 68x64 (4 persistent-mem + 64 tokens), RoPE fused at staging.
__launch_bounds__(256)
__global__ void attn_win(const u16* __restrict__ q_buf, const u16* __restrict__ k_buf,
                         const u16* __restrict__ v_buf, const float* __restrict__ tm,
                         const float* __restrict__ cosT, const float* __restrict__ sinT,
                         u16* __restrict__ o_buf) {
    __shared__ u16 qs[64 * 72];    // [qrow][dh],  stride 72 bf16 (144 B)
    __shared__ u16 ks[80 * 72];    // [key][dh],   rows 0-3 pm, 4-67 tokens, 68-79 zero
    __shared__ u16 vt[64 * 104];   // [dh][key],   stride 104 bf16; keys 68-95 zeroed
    __shared__ u16 ps[64 * 104];   // [qrow][key]; cols 0-95 written in softmax (80-95 = 0)
    const int tid  = threadIdx.x;
    const int lane = tid & 63, w = tid >> 6;
    const int l15 = lane & 15, l4 = lane >> 4;
    const int h = blockIdx.x, wi = blockIdx.y, b = blockIdx.z;
    const int t0 = b * 16384 + wi * 64;

    // zero only what's read-but-unwritten: vt keys 68..95 (14 u32/row), ks rows 68..79
    for (int i = tid; i < 896; i += 256) {
        int d = i / 14, c = i - d * 14;
        *(u32*)&vt[d * 104 + 68 + 2 * c] = 0u;
    }
    for (int i = tid; i < 432; i += 256) ((u32*)ks)[2448 + i] = 0u;   // ks rows 68..79

    // stage task-memory (disjoint from zero regions; no barrier needed yet)
    {
        int r = tid >> 6, d = tid & 63;    // 256 threads == 4x64
        ks[r * 72 + d]   = f2b(tm[(h * 4 + r) * 64 + d]);
        vt[d * 104 + r]  = f2b(tm[2048 + (h * 4 + r) * 64 + d]);
    }
    // stage Q/K with rope
#pragma unroll
    for (int p = tid; p < 2048; p += 256) {
        int row = p >> 5, i = p & 31;
        int n = wi * 64 + row;
        float c = cosT[n * 32 + i], s = sinT[n * 32 + i];
        size_t gbase = (size_t)(t0 + row) * 512 + h * 64 + 2 * i;
        u32 qv = *(const u32*)(q_buf + gbase);
        float x0 = b2f(qv & 0xffffu), x1 = b2f(qv >> 16);
        *(u32*)&qs[row * 72 + 2 * i] = pack2(x0 * c - x1 * s, x1 * c + x0 * s);
        u32 kv = *(const u32*)(k_buf + gbase);
        x0 = b2f(kv & 0xffffu); x1 = b2f(kv >> 16);
        *(u32*)&ks[(row + 4) * 72 + 2 * i] = pack2(x0 * c - x1 * s, x1 * c + x0 * s);
    }
    // stage V transposed (u32 global loads, two u16 LDS stores)
#pragma unroll
    for (int p = tid; p < 2048; p += 256) {
        int row = p >> 5, e = p & 31;
        u32 vv = *(const u32*)(v_buf + (size_t)(t0 + row) * 512 + h * 64 + 2 * e);
        vt[(2 * e) * 104 + 4 + row]     = (u16)(vv & 0xffffu);
        vt[(2 * e + 1) * 104 + 4 + row] = (u16)(vv >> 16);
    }
    __syncthreads();

    // S = Q K^T (wave w owns q-rows [w*16, w*16+16))
    f32x4 sacc[5];
#pragma unroll
    for (int nt = 0; nt < 5; ++nt) sacc[nt] = (f32x4){0.f, 0.f, 0.f, 0.f};
#pragma unroll
    for (int ksi = 0; ksi < 2; ++ksi) {
        short8 a = *(const short8*)&qs[(w * 16 + l15) * 72 + ksi * 32 + l4 * 8];
#pragma unroll
        for (int nt = 0; nt < 5; ++nt) {
            short8 bfr = *(const short8*)&ks[(nt * 16 + l15) * 72 + ksi * 32 + l4 * 8];
            sacc[nt] = __builtin_amdgcn_mfma_f32_16x16x32_bf16(a, bfr, sacc[nt], 0, 0, 0);
        }
    }
    // softmax (rows = w*16 + l4*4 + r; cols spread over 16 lanes x 5 tiles)
    float inv_l[4];
#pragma unroll
    for (int r = 0; r < 4; ++r) {
        float sv[5];
#pragma unroll
        for (int nt = 0; nt < 5; ++nt) {
            float x = sacc[nt][r] * 0.125f;
            if (nt == 4 && l15 >= 4) x = -1e30f;   // keys >= 68 masked
            sv[nt] = x;
        }
        float m = sv[0];
#pragma unroll
        for (int nt = 1; nt < 5; ++nt) m = fmaxf(m, sv[nt]);
#pragma unroll
        for (int off = 1; off < 16; off <<= 1) m = fmaxf(m, __shfl_xor(m, off));
        float sum = 0.f;
#pragma unroll
        for (int nt = 0; nt < 5; ++nt) { sv[nt] = __expf(sv[nt] - m); sum += sv[nt]; }
#pragma unroll
        for (int off = 1; off < 16; off <<= 1) sum += __shfl_xor(sum, off);
        inv_l[r] = 1.f / sum;
        int prow = w * 16 + l4 * 4 + r;
#pragma unroll
        for (int nt = 0; nt < 5; ++nt) ps[prow * 104 + nt * 16 + l15] = f2b(sv[nt]);
        ps[prow * 104 + 80 + l15] = 0;   // pad keys 80..95 for the ksi=2 PV step
    }
    __syncthreads();

    // O = P V  (K-dim padded to 96)
    f32x4 oacc[4];
#pragma unroll
    for (int dt = 0; dt < 4; ++dt) oacc[dt] = (f32x4){0.f, 0.f, 0.f, 0.f};
#pragma unroll
    for (int ksi = 0; ksi < 3; ++ksi) {
        short8 a = *(const short8*)&ps[(w * 16 + l15) * 104 + ksi * 32 + l4 * 8];
#pragma unroll
        for (int dt = 0; dt < 4; ++dt) {
            short8 bfr = *(const short8*)&vt[(dt * 16 + l15) * 104 + ksi * 32 + l4 * 8];
            oacc[dt] = __builtin_amdgcn_mfma_f32_16x16x32_bf16(a, bfr, oacc[dt], 0, 0, 0);
        }
    }
#pragma unroll
    for (int dt = 0; dt < 4; ++dt)
#pragma unroll
        for (int r = 0; r < 4; ++r) {
            int row = w * 16 + l4 * 4 + r;
            o_buf[(size_t)(t0 + row) * 512 + h * 64 + dt * 16 + l15] =
                f2b(oacc[dt][r] * inv_l[r]);
        }
}

// ---------------- launch ----------------
extern "C" void kernel_launch(void* const* d_in, const int* in_sizes, int n_in,
                              void* d_out, int out_size, void* d_ws, size_t ws_size,
                              hipStream_t stream) {
    const float* seq    = (const float*)d_in[0];
    const float* norm_w = (const float*)d_in[5];
    const float* Wq     = (const float*)d_in[6];
    const float* Wkv    = (const float*)d_in[7];
    const float* Wo     = (const float*)d_in[8];
    const float* tmem   = (const float*)d_in[9];
    float* out   = (float*)d_out;
    float* origv = out + 33554432;          // (B=4, h=8, N=16384, d=64)

    char* ws = (char*)d_ws;
    u16* xn    = (u16*)(ws);                 // 64 MB; reused as attn_out after qkv GEMM
    u16* q_buf = (u16*)(ws + 67108864);
    u16* k_buf = (u16*)(ws + 134217728);
    u16* v_buf = (u16*)(ws + 201326592);
    u16* wqkvT = (u16*)(ws + 268435456);     // 1536x512 bf16
    u16* woT   = (u16*)(ws + 268435456 + 1572864);   // 512x512 bf16
    float* cosT = (float*)(ws + 270532608);  // 16384x32
    float* sinT = cosT + 524288;

    rope_tab<<<2048, 256, 0, stream>>>(cosT, sinT);
    conv_w<<<4096, 256, 0, stream>>>(Wq, Wkv, Wo, wqkvT, woT);
    rmsnorm_k<<<16384, 256, 0, stream>>>(seq, norm_w, xn);
    gemm8p<0><<<1536, 512, 0, stream>>>(xn, wqkvT, q_buf, k_buf, v_buf, origv);
    attn_win<<<dim3(8, 256, 4), 256, 0, stream>>>(q_buf, k_buf, v_buf, tmem, cosT, sinT, xn);
    gemm8p<1><<<512, 512, 0, stream>>>(xn, woT, nullptr, nullptr, nullptr, out);
}